// Round 5
// baseline (592.278 us; speedup 1.0000x reference)
//
#include <hip/hip_runtime.h>

#define N_NODES 50000
#define N_EDGES 800000
#define DIM 64
#define NUM_GRAPHS 64

// ---- degree count (atomic int histogram over dst) ----
__global__ void count_deg_kernel(const int* __restrict__ dst, int* __restrict__ cnt, int E) {
  int e = blockIdx.x * blockDim.x + threadIdx.x;
  if (e < E) atomicAdd(&cnt[dst[e]], 1);
}

// ---- scan phase A: block-local exclusive scan of cnt, block sums, fused dis ----
__global__ void scanA_kernel(const int* __restrict__ cnt, int* __restrict__ rowptr,
                             int* __restrict__ bsum, float* __restrict__ dis, int N) {
  __shared__ int wsum[16];
  int i = blockIdx.x * 1024 + threadIdx.x;
  int lane = threadIdx.x & 63, wid = threadIdx.x >> 6;
  int v = (i < N) ? cnt[i] : 0;
  if (i < N) dis[i] = rsqrtf((float)(v + 1));
  int sv = v;
  #pragma unroll
  for (int off = 1; off < 64; off <<= 1) {
    int t = __shfl_up(sv, off, 64);
    if (lane >= off) sv += t;
  }
  if (lane == 63) wsum[wid] = sv;
  __syncthreads();
  if (wid == 0) {
    int wv = (lane < 16) ? wsum[lane] : 0;
    #pragma unroll
    for (int off = 1; off < 16; off <<= 1) {
      int t = __shfl_up(wv, off, 64);
      if (lane >= off) wv += t;
    }
    if (lane < 16) wsum[lane] = wv;
  }
  __syncthreads();
  if (i < N) rowptr[i] = (wid ? wsum[wid - 1] : 0) + (sv - v);
  if (threadIdx.x == 1023) bsum[blockIdx.x] = wsum[15];
}

// ---- scan phase B: scan the (<=64) block sums; set rowptr[N] ----
__global__ void scanB_kernel(int* __restrict__ bsum, int* __restrict__ rowptr, int nb, int N) {
  int t = threadIdx.x;
  int v = (t < nb) ? bsum[t] : 0;
  #pragma unroll
  for (int off = 1; off < 64; off <<= 1) {
    int u = __shfl_up(v, off, 64);
    if (t >= off) v += u;
  }
  if (t < nb) bsum[t] = v;
  if (t == nb - 1) rowptr[N] = v;
}

// ---- scan phase C: add block offsets; also write cursor copy ----
__global__ void scanC_kernel(int* __restrict__ rowptr, const int* __restrict__ bsum,
                             int* __restrict__ cursor, int N) {
  int b = blockIdx.x;
  int i = b * 1024 + threadIdx.x;
  if (i < N) {
    int off = b ? bsum[b - 1] : 0;
    int r = rowptr[i] + off;
    rowptr[i] = r;
    cursor[i] = r;
  }
}

// ---- fill CSR: esrc[pos] = src of each edge, bucketed by dst ----
__global__ void fill_kernel(const int* __restrict__ src, const int* __restrict__ dst,
                            int* __restrict__ cursor, int* __restrict__ esrc, int E) {
  int e = blockIdx.x * blockDim.x + threadIdx.x;
  if (e < E) {
    int d = dst[e];
    int p = atomicAdd(&cursor[d], 1);
    esrc[p] = src[e];
  }
}

__device__ __forceinline__ float rl(float v, int lane) {
  return __int_as_float(__builtin_amdgcn_readlane(__float_as_int(v), lane));
}

// ---- fused layer: out = relu( (dis_i*(sum dis_j F_j + dis_i F_i)) @ W + b ) ----
// One wave per node (grid-stride). Gather: 16-lane float4 groups x 4 edge slots.
// After shfl_xor butterfly every lane holds the aggregated row chunk values;
// GEMM done in-register via v_readlane broadcasts against a per-lane W column.
// LAST: instead of storing the row, dot with Wl and atomically accumulate
// per-graph partial sums.
template <int LAST>
__global__ __launch_bounds__(256) void fused_layer(const float* __restrict__ F,
    const int* __restrict__ rowptr, const int* __restrict__ esrc,
    const float* __restrict__ dis, const float* __restrict__ W,
    const float* __restrict__ b, float* __restrict__ Fout,
    const float* __restrict__ Wl, const int* __restrict__ batch,
    float* __restrict__ partial, int N) {
  int col = threadIdx.x & 63;
  int wid = threadIdx.x >> 6;
  int wave = blockIdx.x * 4 + wid;
  int nwaves = gridDim.x * 4;
  int qc = col & 15;   // float4 chunk index within row
  int qe = col >> 4;   // edge slot 0..3

  float wreg[DIM];     // W[:, col]
  #pragma unroll
  for (int k = 0; k < DIM; ++k) wreg[k] = W[k * DIM + col];
  float bias = b[col];
  float wl = LAST ? Wl[col] : 0.f;

  const float4* __restrict__ F4 = reinterpret_cast<const float4*>(F);

  for (int node = wave; node < N; node += nwaves) {
    int beg = rowptr[node], end = rowptr[node + 1];
    float ax = 0.f, ay = 0.f, az = 0.f, aw = 0.f;
    int j = beg;
    for (; j + 8 <= end; j += 8) {
      int s0 = esrc[j + qe], s1 = esrc[j + 4 + qe];
      float d0 = dis[s0], d1 = dis[s1];
      float4 v0 = F4[(size_t)s0 * 16 + qc];
      float4 v1 = F4[(size_t)s1 * 16 + qc];
      ax = fmaf(v0.x, d0, ax); ay = fmaf(v0.y, d0, ay);
      az = fmaf(v0.z, d0, az); aw = fmaf(v0.w, d0, aw);
      ax = fmaf(v1.x, d1, ax); ay = fmaf(v1.y, d1, ay);
      az = fmaf(v1.z, d1, az); aw = fmaf(v1.w, d1, aw);
    }
    if (j + 4 <= end) {
      int s0 = esrc[j + qe];
      float d0 = dis[s0];
      float4 v0 = F4[(size_t)s0 * 16 + qc];
      ax = fmaf(v0.x, d0, ax); ay = fmaf(v0.y, d0, ay);
      az = fmaf(v0.z, d0, az); aw = fmaf(v0.w, d0, aw);
      j += 4;
    }
    if (j + qe < end) {
      int s = esrc[j + qe];
      float d = dis[s];
      float4 v = F4[(size_t)s * 16 + qc];
      ax = fmaf(v.x, d, ax); ay = fmaf(v.y, d, ay);
      az = fmaf(v.z, d, az); aw = fmaf(v.w, d, aw);
    }
    // reduce the 4 edge-slot groups (lanes differing in bits 4..5);
    // butterfly leaves the sum in ALL lanes of each qc group
    ax += __shfl_xor(ax, 16, 64); ax += __shfl_xor(ax, 32, 64);
    ay += __shfl_xor(ay, 16, 64); ay += __shfl_xor(ay, 32, 64);
    az += __shfl_xor(az, 16, 64); az += __shfl_xor(az, 32, 64);
    aw += __shfl_xor(aw, 16, 64); aw += __shfl_xor(aw, 32, 64);

    // self-loop + symmetric scaling: row chunk qc (cols 4qc..4qc+3)
    float dn = dis[node];
    float4 sf = F4[(size_t)node * 16 + qc];
    float rx = (ax + sf.x * dn) * dn;
    float ry = (ay + sf.y * dn) * dn;
    float rz = (az + sf.z * dn) * dn;
    float rw = (aw + sf.w * dn) * dn;

    // in-register GEMM: out[col] = sum_k row[k] * W[k][col] + b[col]
    // row[4c+m] lives in lane c (chunk c); readlane broadcasts it
    float acc = bias;
    #pragma unroll
    for (int c = 0; c < 16; ++c) {
      acc = fmaf(rl(rx, c), wreg[4 * c + 0], acc);
      acc = fmaf(rl(ry, c), wreg[4 * c + 1], acc);
      acc = fmaf(rl(rz, c), wreg[4 * c + 2], acc);
      acc = fmaf(rl(rw, c), wreg[4 * c + 3], acc);
    }
    float v = fmaxf(acc, 0.f);
    if (!LAST) {
      Fout[(size_t)node * DIM + col] = v;
    } else {
      float y = v * wl;
      #pragma unroll
      for (int off = 32; off > 0; off >>= 1) y += __shfl_xor(y, off, 64);
      if (col == 0) atomicAdd(&partial[batch[node]], y);
    }
  }
}

// ---- finalize: out[g] = partial[g]/count_g + bl ----
__global__ void pool_final_kernel(const float* __restrict__ partial, const int* __restrict__ batch,
                                  const float* __restrict__ bl, float* __restrict__ out, int N) {
  int g = threadIdx.x;  // 64 threads
  int lo = 0, hi = N;
  while (lo < hi) { int m = (lo + hi) >> 1; if (batch[m] < g) lo = m + 1; else hi = m; }
  int start = lo;
  hi = N;
  while (lo < hi) { int m = (lo + hi) >> 1; if (batch[m] < g + 1) lo = m + 1; else hi = m; }
  float c = fmaxf((float)(lo - start), 1.f);
  out[g] = partial[g] / c + bl[0];
}

extern "C" void kernel_launch(void* const* d_in, const int* in_sizes, int n_in,
                              void* d_out, int out_size, void* d_ws, size_t ws_size,
                              hipStream_t stream) {
  const float* x     = (const float*)d_in[0];
  const int*   ei    = (const int*)d_in[1];   // int64 in reference, delivered as int32
  const int*   batch = (const int*)d_in[2];
  const float* W1 = (const float*)d_in[3];
  const float* b1 = (const float*)d_in[4];
  const float* W2 = (const float*)d_in[5];
  const float* b2 = (const float*)d_in[6];
  const float* W3 = (const float*)d_in[7];
  const float* b3 = (const float*)d_in[8];
  const float* Wl = (const float*)d_in[9];
  const float* bl = (const float*)d_in[10];
  float* out = (float*)d_out;

  const int* srcp = ei;
  const int* dstp = ei + N_EDGES;

  char* ws = (char*)d_ws;
  size_t off = 0;
  auto alloc = [&](size_t bytes) { void* p = ws + off; off += (bytes + 255) & ~(size_t)255; return p; };
  int*   cnt     = (int*)  alloc((size_t)N_NODES * 4);        // reused as cursor
  float* dis     = (float*)alloc((size_t)N_NODES * 4);
  int*   rowptr  = (int*)  alloc((size_t)(N_NODES + 1) * 4);
  int*   bsum    = (int*)  alloc(64 * 4);
  float* partial = (float*)alloc(NUM_GRAPHS * 4);
  int*   esrc    = (int*)  alloc((size_t)N_EDGES * 4);
  float* bufA    = (float*)alloc((size_t)N_NODES * DIM * 4);
  float* bufB    = (float*)alloc((size_t)N_NODES * DIM * 4);

  const int NB = (N_NODES + 1023) / 1024;  // 49

  // ---- CSR build ----
  hipMemsetAsync(cnt, 0, (size_t)N_NODES * 4, stream);
  count_deg_kernel<<<(N_EDGES + 255) / 256, 256, 0, stream>>>(dstp, cnt, N_EDGES);
  scanA_kernel<<<NB, 1024, 0, stream>>>(cnt, rowptr, bsum, dis, N_NODES);
  scanB_kernel<<<1, 64, 0, stream>>>(bsum, rowptr, NB, N_NODES);
  scanC_kernel<<<NB, 1024, 0, stream>>>(rowptr, bsum, cnt, N_NODES);
  fill_kernel<<<(N_EDGES + 255) / 256, 256, 0, stream>>>(srcp, dstp, cnt, esrc, N_EDGES);

  // ---- 3 fused GCN layers (aggregate + GEMM + bias + relu in one kernel) ----
  const int FB = 2048;  // 8192 waves, ~6 nodes/wave
  fused_layer<0><<<FB, 256, 0, stream>>>(x,    rowptr, esrc, dis, W1, b1, bufA,
                                         nullptr, nullptr, nullptr, N_NODES);
  fused_layer<0><<<FB, 256, 0, stream>>>(bufA, rowptr, esrc, dis, W2, b2, bufB,
                                         nullptr, nullptr, nullptr, N_NODES);
  hipMemsetAsync(partial, 0, NUM_GRAPHS * 4, stream);
  fused_layer<1><<<FB, 256, 0, stream>>>(bufB, rowptr, esrc, dis, W3, b3, nullptr,
                                         Wl, batch, partial, N_NODES);
  pool_final_kernel<<<1, 64, 0, stream>>>(partial, batch, bl, out, N_NODES);
}

// Round 6
// 252.989 us; speedup vs baseline: 2.3411x; 2.3411x over previous
//
#include <hip/hip_runtime.h>

#define N_NODES 50000
#define N_EDGES 800000
#define DIM 64
#define NUM_GRAPHS 64
#define NPART 8
#define PART_NODES 6250   // N_NODES / NPART exactly

// ---- degree count, XCD-partitioned: partition p owns dst range, so cnt
// lines are written from a single XCD (no cross-XCD line bouncing) ----
__global__ void count_deg_kernel(const int* __restrict__ dst, int* __restrict__ cnt, int E) {
  int p = blockIdx.x & 7;
  int lo = p * PART_NODES, hi = lo + PART_NODES;
  int stride = (gridDim.x >> 3) * blockDim.x;
  for (int e = (blockIdx.x >> 3) * blockDim.x + threadIdx.x; e < E; e += stride) {
    int d = dst[e];
    if (d >= lo && d < hi) atomicAdd(&cnt[d], 1);
  }
}

// ---- scan phase A: block-local exclusive scan of cnt, block sums, fused dis ----
__global__ void scanA_kernel(const int* __restrict__ cnt, int* __restrict__ rowptr,
                             int* __restrict__ bsum, float* __restrict__ dis, int N) {
  __shared__ int wsum[16];
  int i = blockIdx.x * 1024 + threadIdx.x;
  int lane = threadIdx.x & 63, wid = threadIdx.x >> 6;
  int v = (i < N) ? cnt[i] : 0;
  if (i < N) dis[i] = rsqrtf((float)(v + 1));
  int sv = v;
  #pragma unroll
  for (int off = 1; off < 64; off <<= 1) {
    int t = __shfl_up(sv, off, 64);
    if (lane >= off) sv += t;
  }
  if (lane == 63) wsum[wid] = sv;
  __syncthreads();
  if (wid == 0) {
    int wv = (lane < 16) ? wsum[lane] : 0;
    #pragma unroll
    for (int off = 1; off < 16; off <<= 1) {
      int t = __shfl_up(wv, off, 64);
      if (lane >= off) wv += t;
    }
    if (lane < 16) wsum[lane] = wv;
  }
  __syncthreads();
  if (i < N) rowptr[i] = (wid ? wsum[wid - 1] : 0) + (sv - v);
  if (threadIdx.x == 1023) bsum[blockIdx.x] = wsum[15];
}

// ---- scan phase B: scan the (<=64) block sums; set rowptr[N] ----
__global__ void scanB_kernel(int* __restrict__ bsum, int* __restrict__ rowptr, int nb, int N) {
  int t = threadIdx.x;
  int v = (t < nb) ? bsum[t] : 0;
  #pragma unroll
  for (int off = 1; off < 64; off <<= 1) {
    int u = __shfl_up(v, off, 64);
    if (t >= off) v += u;
  }
  if (t < nb) bsum[t] = v;
  if (t == nb - 1) rowptr[N] = v;
}

// ---- scan phase C: add block offsets; also write cursor copy ----
__global__ void scanC_kernel(int* __restrict__ rowptr, const int* __restrict__ bsum,
                             int* __restrict__ cursor, int N) {
  int b = blockIdx.x;
  int i = b * 1024 + threadIdx.x;
  if (i < N) {
    int off = b ? bsum[b - 1] : 0;
    int r = rowptr[i] + off;
    rowptr[i] = r;
    cursor[i] = r;
  }
}

// ---- fill CSR, XCD-partitioned: partition p owns dst range -> cursor and
// esrc lines are written only from one XCD; each line written back once ----
__global__ void fill_kernel(const int* __restrict__ src, const int* __restrict__ dst,
                            int* __restrict__ cursor, int* __restrict__ esrc, int E) {
  int p = blockIdx.x & 7;
  int lo = p * PART_NODES, hi = lo + PART_NODES;
  int stride = (gridDim.x >> 3) * blockDim.x;
  for (int e = (blockIdx.x >> 3) * blockDim.x + threadIdx.x; e < E; e += stride) {
    int d = dst[e];
    if (d >= lo && d < hi) {
      int pos = atomicAdd(&cursor[d], 1);
      esrc[pos] = src[e];
    }
  }
}

// ---- aggregate: A_i = dis_i * ( sum_{j in in(i)} dis_j * F_j  +  dis_i * F_i ) ----
// one wave per node; 16-lane float4 groups, 4 edges/slot, 8 edges in flight
__global__ __launch_bounds__(256) void aggregate_kernel(const float* __restrict__ F,
    const int* __restrict__ rowptr, const int* __restrict__ esrc,
    const float* __restrict__ dis, float* __restrict__ A, int N) {
  int node = blockIdx.x * 4 + (threadIdx.x >> 6);
  if (node >= N) return;
  int lane = threadIdx.x & 63;
  int qc = lane & 15;   // float4 column index within row
  int qe = lane >> 4;   // edge slot 0..3
  const float4* __restrict__ F4 = reinterpret_cast<const float4*>(F);
  int beg = rowptr[node], end = rowptr[node + 1];
  float ax = 0.f, ay = 0.f, az = 0.f, aw = 0.f;
  int j = beg;
  for (; j + 8 <= end; j += 8) {
    int s0 = esrc[j + qe], s1 = esrc[j + 4 + qe];
    float d0 = dis[s0], d1 = dis[s1];
    float4 v0 = F4[(size_t)s0 * 16 + qc];
    float4 v1 = F4[(size_t)s1 * 16 + qc];
    ax = fmaf(v0.x, d0, ax); ay = fmaf(v0.y, d0, ay);
    az = fmaf(v0.z, d0, az); aw = fmaf(v0.w, d0, aw);
    ax = fmaf(v1.x, d1, ax); ay = fmaf(v1.y, d1, ay);
    az = fmaf(v1.z, d1, az); aw = fmaf(v1.w, d1, aw);
  }
  if (j + 4 <= end) {
    int s0 = esrc[j + qe];
    float d0 = dis[s0];
    float4 v0 = F4[(size_t)s0 * 16 + qc];
    ax = fmaf(v0.x, d0, ax); ay = fmaf(v0.y, d0, ay);
    az = fmaf(v0.z, d0, az); aw = fmaf(v0.w, d0, aw);
    j += 4;
  }
  if (j + qe < end) {
    int s = esrc[j + qe];
    float d = dis[s];
    float4 v = F4[(size_t)s * 16 + qc];
    ax = fmaf(v.x, d, ax); ay = fmaf(v.y, d, ay);
    az = fmaf(v.z, d, az); aw = fmaf(v.w, d, aw);
  }
  // reduce the 4 edge-slot groups (lanes differ in bits 4..5)
  ax += __shfl_xor(ax, 16, 64); ax += __shfl_xor(ax, 32, 64);
  ay += __shfl_xor(ay, 16, 64); ay += __shfl_xor(ay, 32, 64);
  az += __shfl_xor(az, 16, 64); az += __shfl_xor(az, 32, 64);
  aw += __shfl_xor(aw, 16, 64); aw += __shfl_xor(aw, 32, 64);
  if (qe == 0) {
    float dn = dis[node];
    float4 sf = F4[(size_t)node * 16 + qc];
    float4 r;
    r.x = (ax + sf.x * dn) * dn;
    r.y = (ay + sf.y * dn) * dn;
    r.z = (az + sf.z * dn) * dn;
    r.w = (aw + sf.w * dn) * dn;
    reinterpret_cast<float4*>(A)[(size_t)node * 16 + qc] = r;
  }
}

// ---- fused GEMM + bias + relu: F = relu(A @ W + b); 64 rows/block ----
__global__ __launch_bounds__(256) void gemm_bias_relu(const float* __restrict__ X,
    const float* __restrict__ W, const float* __restrict__ b,
    float* __restrict__ F, int N) {
  __shared__ float4 Xs[64][16];
  int col = threadIdx.x & 63, wid = threadIdx.x >> 6;
  float wreg[DIM];
  #pragma unroll
  for (int k = 0; k < DIM; ++k) wreg[k] = W[k * DIM + col];
  float bias = b[col];
  int row0 = blockIdx.x * 64;
  for (int i = threadIdx.x; i < 64 * 16; i += 256) {
    int r = i >> 4, c = i & 15;
    int gr = row0 + r;
    Xs[r][c] = (gr < N) ? reinterpret_cast<const float4*>(X)[(size_t)gr * 16 + c]
                        : make_float4(0.f, 0.f, 0.f, 0.f);
  }
  __syncthreads();
  for (int rr = 0; rr < 16; ++rr) {
    int lr = wid * 16 + rr;
    int row = row0 + lr;
    if (row >= N) break;   // uniform per wave
    float a0 = 0.f, a1 = 0.f, a2 = 0.f, a3 = 0.f;
    #pragma unroll
    for (int kk = 0; kk < 16; ++kk) {
      float4 xv = Xs[lr][kk];
      a0 = fmaf(xv.x, wreg[4 * kk + 0], a0);
      a1 = fmaf(xv.y, wreg[4 * kk + 1], a1);
      a2 = fmaf(xv.z, wreg[4 * kk + 2], a2);
      a3 = fmaf(xv.w, wreg[4 * kk + 3], a3);
    }
    float v = a0 + a1 + a2 + a3 + bias;
    F[(size_t)row * DIM + col] = fmaxf(v, 0.f);
  }
}

// ---- layer-3 fused: y = relu(A@W3+b3) . Wl, block-level graph partials ----
__global__ __launch_bounds__(256) void gemm_dot_kernel(const float* __restrict__ X,
    const float* __restrict__ W, const float* __restrict__ b, const float* __restrict__ Wl,
    const int* __restrict__ batch, float* __restrict__ partial, int N) {
  __shared__ float4 Xs[64][16];
  __shared__ float yv[64];
  __shared__ float gpart[NUM_GRAPHS];
  int col = threadIdx.x & 63, wid = threadIdx.x >> 6;
  float wreg[DIM];
  #pragma unroll
  for (int k = 0; k < DIM; ++k) wreg[k] = W[k * DIM + col];
  float bias = b[col];
  float wl = Wl[col];
  int row0 = blockIdx.x * 64;
  if (threadIdx.x < 64) { yv[threadIdx.x] = 0.f; gpart[threadIdx.x] = 0.f; }
  for (int i = threadIdx.x; i < 64 * 16; i += 256) {
    int r = i >> 4, c = i & 15;
    int gr = row0 + r;
    Xs[r][c] = (gr < N) ? reinterpret_cast<const float4*>(X)[(size_t)gr * 16 + c]
                        : make_float4(0.f, 0.f, 0.f, 0.f);
  }
  __syncthreads();
  for (int rr = 0; rr < 16; ++rr) {
    int lr = wid * 16 + rr;
    int row = row0 + lr;
    if (row >= N) break;   // uniform per wave
    float a0 = 0.f, a1 = 0.f, a2 = 0.f, a3 = 0.f;
    #pragma unroll
    for (int kk = 0; kk < 16; ++kk) {
      float4 xv = Xs[lr][kk];
      a0 = fmaf(xv.x, wreg[4 * kk + 0], a0);
      a1 = fmaf(xv.y, wreg[4 * kk + 1], a1);
      a2 = fmaf(xv.z, wreg[4 * kk + 2], a2);
      a3 = fmaf(xv.w, wreg[4 * kk + 3], a3);
    }
    float v = fmaxf(a0 + a1 + a2 + a3 + bias, 0.f);
    float y = v * wl;
    #pragma unroll
    for (int off = 32; off > 0; off >>= 1) y += __shfl_down(y, off, 64);
    if (col == 0) yv[lr] = y;
  }
  __syncthreads();
  if (threadIdx.x < 64) {
    int row = row0 + threadIdx.x;
    if (row < N) atomicAdd(&gpart[batch[row]], yv[threadIdx.x]);
  }
  __syncthreads();
  if (threadIdx.x < NUM_GRAPHS) {
    int glo = batch[row0];
    int ghi = batch[min(row0 + 63, N - 1)];
    int g = threadIdx.x;
    if (g >= glo && g <= ghi) atomicAdd(&partial[g], gpart[g]);
  }
}

// ---- finalize: out[g] = partial[g]/count_g + bl ----
__global__ void pool_final_kernel(const float* __restrict__ partial, const int* __restrict__ batch,
                                  const float* __restrict__ bl, float* __restrict__ out, int N) {
  int g = threadIdx.x;  // 64 threads
  int lo = 0, hi = N;
  while (lo < hi) { int m = (lo + hi) >> 1; if (batch[m] < g) lo = m + 1; else hi = m; }
  int start = lo;
  hi = N;
  while (lo < hi) { int m = (lo + hi) >> 1; if (batch[m] < g + 1) lo = m + 1; else hi = m; }
  float c = fmaxf((float)(lo - start), 1.f);
  out[g] = partial[g] / c + bl[0];
}

extern "C" void kernel_launch(void* const* d_in, const int* in_sizes, int n_in,
                              void* d_out, int out_size, void* d_ws, size_t ws_size,
                              hipStream_t stream) {
  const float* x     = (const float*)d_in[0];
  const int*   ei    = (const int*)d_in[1];   // int64 in reference, delivered as int32
  const int*   batch = (const int*)d_in[2];
  const float* W1 = (const float*)d_in[3];
  const float* b1 = (const float*)d_in[4];
  const float* W2 = (const float*)d_in[5];
  const float* b2 = (const float*)d_in[6];
  const float* W3 = (const float*)d_in[7];
  const float* b3 = (const float*)d_in[8];
  const float* Wl = (const float*)d_in[9];
  const float* bl = (const float*)d_in[10];
  float* out = (float*)d_out;

  const int* srcp = ei;
  const int* dstp = ei + N_EDGES;

  char* ws = (char*)d_ws;
  size_t off = 0;
  auto alloc = [&](size_t bytes) { void* p = ws + off; off += (bytes + 255) & ~(size_t)255; return p; };
  int*   cnt     = (int*)  alloc((size_t)N_NODES * 4);        // reused as cursor
  float* dis     = (float*)alloc((size_t)N_NODES * 4);
  int*   rowptr  = (int*)  alloc((size_t)(N_NODES + 1) * 4);
  int*   bsum    = (int*)  alloc(64 * 4);
  float* partial = (float*)alloc(NUM_GRAPHS * 4);
  int*   esrc    = (int*)  alloc((size_t)N_EDGES * 4);
  float* bufA    = (float*)alloc((size_t)N_NODES * DIM * 4);
  float* bufB    = (float*)alloc((size_t)N_NODES * DIM * 4);

  const int NB = (N_NODES + 1023) / 1024;  // 49

  // ---- CSR build (edge passes XCD-partitioned by dst range) ----
  hipMemsetAsync(cnt, 0, (size_t)N_NODES * 4, stream);
  count_deg_kernel<<<1024, 256, 0, stream>>>(dstp, cnt, N_EDGES);
  scanA_kernel<<<NB, 1024, 0, stream>>>(cnt, rowptr, bsum, dis, N_NODES);
  scanB_kernel<<<1, 64, 0, stream>>>(bsum, rowptr, NB, N_NODES);
  scanC_kernel<<<NB, 1024, 0, stream>>>(rowptr, bsum, cnt, N_NODES);
  fill_kernel<<<1024, 256, 0, stream>>>(srcp, dstp, cnt, esrc, N_EDGES);

  // ---- 3 GCN layers ----
  const int GB = (N_NODES + 63) / 64;  // 782
  aggregate_kernel<<<(N_NODES + 3) / 4, 256, 0, stream>>>(x, rowptr, esrc, dis, bufA, N_NODES);
  gemm_bias_relu<<<GB, 256, 0, stream>>>(bufA, W1, b1, bufB, N_NODES);
  aggregate_kernel<<<(N_NODES + 3) / 4, 256, 0, stream>>>(bufB, rowptr, esrc, dis, bufA, N_NODES);
  gemm_bias_relu<<<GB, 256, 0, stream>>>(bufA, W2, b2, bufB, N_NODES);
  aggregate_kernel<<<(N_NODES + 3) / 4, 256, 0, stream>>>(bufB, rowptr, esrc, dis, bufA, N_NODES);
  hipMemsetAsync(partial, 0, NUM_GRAPHS * 4, stream);
  gemm_dot_kernel<<<GB, 256, 0, stream>>>(bufA, W3, b3, Wl, batch, partial, N_NODES);
  pool_final_kernel<<<1, 64, 0, stream>>>(partial, batch, bl, out, N_NODES);
}